// Round 4
// baseline (451.449 us; speedup 1.0000x reference)
//
#include <hip/hip_runtime.h>
#include <math.h>

#define BATCH 1024
#define NU 1000
#define NI 1000
#define EDIM 128
#define INROW 66    // 2 + UF + IF
#define IN_SIZE 320 // E + UF + E + IF
#define OUTROW 258  // 2 + 2*E
#define G 4         // batch rows per compute block

typedef float f32x4 __attribute__((ext_vector_type(4)));

// ---------------------------------------------------------------------------
// Pure streaming copy: umem -> dst_u, imem -> dst_i, including stale id-rows
// (compute overwrites those afterwards). Branchless, fully unrolled,
// nontemporal stores. grid (5120, 2), 256 threads, 25 float4 per thread.
// ---------------------------------------------------------------------------
__global__ __launch_bounds__(256) void limnet_stream_copy(
    const f32x4* __restrict__ usrc, const f32x4* __restrict__ isrc,
    f32x4* __restrict__ udst, f32x4* __restrict__ idst)
{
    const f32x4* __restrict__ src = blockIdx.y ? isrc : usrc;
    f32x4* __restrict__ dst = blockIdx.y ? idst : udst;
    long p = (long)blockIdx.x * 6400 + threadIdx.x;
    #pragma unroll
    for (int i = 0; i < 25; ++i, p += 256) {
        f32x4 v = src[p];
        __builtin_nontemporal_store(v, &dst[p]);
    }
}

// ---------------------------------------------------------------------------
// Compute kernel: per block handles G=4 batch rows.
//   gi = x @ w_ih^T (768 rows: 384 user + 384 item), gates, L2-normalize.
//   Writes out rows AND scatters new vectors into the dst memory sections.
// ---------------------------------------------------------------------------
__global__ __launch_bounds__(256) void limnet_compute(
    const float* __restrict__ inputs,
    const float* __restrict__ umem,
    const float* __restrict__ imem,
    const float* __restrict__ w_u, const float* __restrict__ bih_u, const float* __restrict__ bhh_u,
    const float* __restrict__ w_i, const float* __restrict__ bih_i, const float* __restrict__ bhh_i,
    float* __restrict__ out,
    float* __restrict__ udst, float* __restrict__ idst)
{
    __shared__ float xx[G][640];   // x_u duplicated: x_i[k] == xx[160+k]
    __shared__ float gi[G][768];   // 384 user rows then 384 item rows
    __shared__ float psum[4][G];
    __shared__ int   ids[G][2];

    const int t = threadIdx.x;
    const int wave = t >> 6, lane = t & 63;
    const int lane16 = lane & 15, sub = lane >> 4;
    const int b0 = blockIdx.x * G;

    // ---- stage x vectors ----
    for (int g = 0; g < G; ++g) {
        const int b = b0 + g;
        const float* inrow = inputs + (long)b * INROW;
        const int uid = (int)inrow[0];
        const int iid = (int)inrow[1];
        if (t == 0) { ids[g][0] = uid; ids[g][1] = iid; }
        if (t < 128) {
            float v = umem[((long)b * NU + uid) * EDIM + t];
            xx[g][t]       = v;  xx[g][320 + t] = v;
            float w = imem[((long)b * NI + iid) * EDIM + t];
            xx[g][160 + t] = w;  xx[g][480 + t] = w;
        } else {
            int s = t - 128;
            if (s < 32)      { float v = inrow[2 + s];  xx[g][128 + s] = v; xx[g][448 + s] = v; }
            else if (s < 64) { int s2 = s - 32; float v = inrow[34 + s2]; xx[g][288 + s2] = v; xx[g][608 + s2] = v; }
        }
    }
    __syncthreads();

    // ---- hoist x fragments into registers (wave-uniform xoff) ----
    const int isItemW = (wave >= 2);
    const int xoff = isItemW ? 160 : 0;
    f32x4 xv[G][5];
    #pragma unroll
    for (int g = 0; g < G; ++g)
        #pragma unroll
        for (int i = 0; i < 5; ++i)
            xv[g][i] = *(const f32x4*)&xx[g][xoff + lane16 * 4 + i * 64];

    // ---- GEMM: 16 lanes per row, 4 rows in flight per wave ----
    const float* wbase = isItemW ? w_i : w_u;
    const int rbase = (wave & 1) * 192;
    const int gibase = isItemW ? 384 : 0;
    for (int it = 0; it < 48; ++it) {
        const int row = rbase + it * 4 + sub;
        const float* wrow = wbase + (long)row * IN_SIZE;
        float acc[G] = {0.f, 0.f, 0.f, 0.f};
        #pragma unroll
        for (int i = 0; i < 5; ++i) {
            const f32x4 wv = *(const f32x4*)&wrow[lane16 * 4 + i * 64];
            #pragma unroll
            for (int g = 0; g < G; ++g)
                acc[g] += wv.x * xv[g][i].x + wv.y * xv[g][i].y
                        + wv.z * xv[g][i].z + wv.w * xv[g][i].w;
        }
        #pragma unroll
        for (int off = 8; off >= 1; off >>= 1) {
            #pragma unroll
            for (int g = 0; g < G; ++g) acc[g] += __shfl_xor(acc[g], off);
        }
        if (lane16 == 0) {
            #pragma unroll
            for (int g = 0; g < G; ++g) gi[g][gibase + row] = acc[g];
        }
    }
    __syncthreads();

    // ---- gates + L2 norm: t<128 -> user dim d=t ; t>=128 -> item dim d=t-128 ----
    const int isItem = (t >= 128);
    const int d = isItem ? (t - 128) : t;
    const float* bih = isItem ? bih_i : bih_u;
    const float* bhh = isItem ? bhh_i : bhh_u;
    const float br = bih[d]       + bhh[d];
    const float bz = bih[128 + d] + bhh[128 + d];
    const float bn = bih[256 + d];
    const float hn = bhh[256 + d];
    const int gib = isItem ? 384 : 0;

    float val[G], ss[G];
    #pragma unroll
    for (int g = 0; g < G; ++g) {
        float ir  = gi[g][gib + d];
        float iz  = gi[g][gib + 128 + d];
        float inn = gi[g][gib + 256 + d];
        float r = 1.f / (1.f + expf(-(ir + br)));
        float z = 1.f / (1.f + expf(-(iz + bz)));
        float n = tanhf(inn + bn + r * hn);
        val[g] = (1.f - z) * n;
        ss[g]  = val[g] * val[g];
    }
    #pragma unroll
    for (int off = 32; off >= 1; off >>= 1) {
        #pragma unroll
        for (int g = 0; g < G; ++g) ss[g] += __shfl_xor(ss[g], off);
    }
    if (lane == 0) {
        #pragma unroll
        for (int g = 0; g < G; ++g) psum[wave][g] = ss[g];
    }
    __syncthreads();

    #pragma unroll
    for (int g = 0; g < G; ++g) {
        float s = isItem ? (psum[2][g] + psum[3][g]) : (psum[0][g] + psum[1][g]);
        float denom = fmaxf(sqrtf(s), 1e-12f);
        float nv = val[g] / denom;
        const int b = b0 + g;
        out[(long)b * OUTROW + 2 + (isItem ? 128 : 0) + d] = nv;
        if (isItem) idst[((long)b * NI + ids[g][1]) * EDIM + d] = nv;
        else        udst[((long)b * NU + ids[g][0]) * EDIM + d] = nv;
    }
    if (t < 2 * G) {
        int g = t >> 1, col = t & 1;
        out[(long)(b0 + g) * OUTROW + col] = (float)ids[g][col];
    }
}

extern "C" void kernel_launch(void* const* d_in, const int* in_sizes, int n_in,
                              void* d_out, int out_size, void* d_ws, size_t ws_size,
                              hipStream_t stream) {
    const float* inputs = (const float*)d_in[0];
    const float* umem   = (const float*)d_in[1];
    const float* imem   = (const float*)d_in[2];
    const float* w_u    = (const float*)d_in[3];
    const float* bih_u  = (const float*)d_in[4];
    const float* bhh_u  = (const float*)d_in[5];
    const float* w_i    = (const float*)d_in[6];
    const float* bih_i  = (const float*)d_in[7];
    const float* bhh_i  = (const float*)d_in[8];
    float* out = (float*)d_out;

    const long OUTSEC = (long)BATCH * OUTROW;       // 264192
    const long MEMSZ  = (long)BATCH * NU * EDIM;    // 131072000
    float* udst = out + OUTSEC;
    float* idst = out + OUTSEC + MEMSZ;

    // 1) Big streaming copy first — no dependency on compute.
    dim3 cgrid(5120, 2);
    limnet_stream_copy<<<cgrid, 256, 0, stream>>>(
        (const f32x4*)umem, (const f32x4*)imem, (f32x4*)udst, (f32x4*)idst);

    // 2) Compute GRU + normalize; writes out section and scatters id-rows
    //    into the already-copied dst sections.
    limnet_compute<<<BATCH / G, 256, 0, stream>>>(
        inputs, umem, imem, w_u, bih_u, bhh_u, w_i, bih_i, bhh_i,
        out, udst, idst);
}

// Round 5
// 421.172 us; speedup vs baseline: 1.0719x; 1.0719x over previous
//
#include <hip/hip_runtime.h>
#include <math.h>

#define BATCH 1024
#define NU 1000
#define NI 1000
#define EDIM 128
#define INROW 66    // 2 + UF + IF
#define IN_SIZE 320 // E + UF + E + IF
#define OUTROW 258  // 2 + 2*E
#define G 4         // batch rows per compute block

typedef float f32x4 __attribute__((ext_vector_type(4)));

// ---------------------------------------------------------------------------
// Pure streaming copy: umem -> dst_u, imem -> dst_i, including stale id-rows
// (compute overwrites those afterwards). Branchless. NT load (no L2 read-
// allocate) + NT store, 5-deep unroll (keeps VGPR low -> 8 waves/SIMD).
// grid (5120, 2), 256 threads, 25 float4 per thread.
// ---------------------------------------------------------------------------
__global__ __launch_bounds__(256) void limnet_stream_copy(
    const f32x4* __restrict__ usrc, const f32x4* __restrict__ isrc,
    f32x4* __restrict__ udst, f32x4* __restrict__ idst)
{
    const f32x4* __restrict__ src = blockIdx.y ? isrc : usrc;
    f32x4* __restrict__ dst = blockIdx.y ? idst : udst;
    long p = (long)blockIdx.x * 6400 + threadIdx.x;
    #pragma unroll 5
    for (int i = 0; i < 25; ++i, p += 256) {
        f32x4 v = __builtin_nontemporal_load(&src[p]);
        __builtin_nontemporal_store(v, &dst[p]);
    }
}

// ---------------------------------------------------------------------------
// Compute kernel: per block handles G=4 batch rows.
//   gi = x @ w_ih^T (768 rows: 384 user + 384 item), gates, L2-normalize.
//   Writes out rows AND scatters new vectors into the dst memory sections.
// ---------------------------------------------------------------------------
__global__ __launch_bounds__(256) void limnet_compute(
    const float* __restrict__ inputs,
    const float* __restrict__ umem,
    const float* __restrict__ imem,
    const float* __restrict__ w_u, const float* __restrict__ bih_u, const float* __restrict__ bhh_u,
    const float* __restrict__ w_i, const float* __restrict__ bih_i, const float* __restrict__ bhh_i,
    float* __restrict__ out,
    float* __restrict__ udst, float* __restrict__ idst)
{
    __shared__ float xx[G][640];   // x_u duplicated: x_i[k] == xx[160+k]
    __shared__ float gi[G][768];   // 384 user rows then 384 item rows
    __shared__ float psum[4][G];
    __shared__ int   ids[G][2];

    const int t = threadIdx.x;
    const int wave = t >> 6, lane = t & 63;
    const int lane16 = lane & 15, sub = lane >> 4;
    const int b0 = blockIdx.x * G;

    // ---- stage x vectors ----
    for (int g = 0; g < G; ++g) {
        const int b = b0 + g;
        const float* inrow = inputs + (long)b * INROW;
        const int uid = (int)inrow[0];
        const int iid = (int)inrow[1];
        if (t == 0) { ids[g][0] = uid; ids[g][1] = iid; }
        if (t < 128) {
            float v = umem[((long)b * NU + uid) * EDIM + t];
            xx[g][t]       = v;  xx[g][320 + t] = v;
            float w = imem[((long)b * NI + iid) * EDIM + t];
            xx[g][160 + t] = w;  xx[g][480 + t] = w;
        } else {
            int s = t - 128;
            if (s < 32)      { float v = inrow[2 + s];  xx[g][128 + s] = v; xx[g][448 + s] = v; }
            else if (s < 64) { int s2 = s - 32; float v = inrow[34 + s2]; xx[g][288 + s2] = v; xx[g][608 + s2] = v; }
        }
    }
    __syncthreads();

    // ---- hoist x fragments into registers (wave-uniform xoff) ----
    const int isItemW = (wave >= 2);
    const int xoff = isItemW ? 160 : 0;
    f32x4 xv[G][5];
    #pragma unroll
    for (int g = 0; g < G; ++g)
        #pragma unroll
        for (int i = 0; i < 5; ++i)
            xv[g][i] = *(const f32x4*)&xx[g][xoff + lane16 * 4 + i * 64];

    // ---- GEMM: 16 lanes per row, 4 rows in flight per wave ----
    const float* wbase = isItemW ? w_i : w_u;
    const int rbase = (wave & 1) * 192;
    const int gibase = isItemW ? 384 : 0;
    for (int it = 0; it < 48; ++it) {
        const int row = rbase + it * 4 + sub;
        const float* wrow = wbase + (long)row * IN_SIZE;
        float acc[G] = {0.f, 0.f, 0.f, 0.f};
        #pragma unroll
        for (int i = 0; i < 5; ++i) {
            const f32x4 wv = *(const f32x4*)&wrow[lane16 * 4 + i * 64];
            #pragma unroll
            for (int g = 0; g < G; ++g)
                acc[g] += wv.x * xv[g][i].x + wv.y * xv[g][i].y
                        + wv.z * xv[g][i].z + wv.w * xv[g][i].w;
        }
        #pragma unroll
        for (int off = 8; off >= 1; off >>= 1) {
            #pragma unroll
            for (int g = 0; g < G; ++g) acc[g] += __shfl_xor(acc[g], off);
        }
        if (lane16 == 0) {
            #pragma unroll
            for (int g = 0; g < G; ++g) gi[g][gibase + row] = acc[g];
        }
    }
    __syncthreads();

    // ---- gates + L2 norm: t<128 -> user dim d=t ; t>=128 -> item dim d=t-128 ----
    const int isItem = (t >= 128);
    const int d = isItem ? (t - 128) : t;
    const float* bih = isItem ? bih_i : bih_u;
    const float* bhh = isItem ? bhh_i : bhh_u;
    const float br = bih[d]       + bhh[d];
    const float bz = bih[128 + d] + bhh[128 + d];
    const float bn = bih[256 + d];
    const float hn = bhh[256 + d];
    const int gib = isItem ? 384 : 0;

    float val[G], ss[G];
    #pragma unroll
    for (int g = 0; g < G; ++g) {
        float ir  = gi[g][gib + d];
        float iz  = gi[g][gib + 128 + d];
        float inn = gi[g][gib + 256 + d];
        float r = 1.f / (1.f + expf(-(ir + br)));
        float z = 1.f / (1.f + expf(-(iz + bz)));
        float n = tanhf(inn + bn + r * hn);
        val[g] = (1.f - z) * n;
        ss[g]  = val[g] * val[g];
    }
    #pragma unroll
    for (int off = 32; off >= 1; off >>= 1) {
        #pragma unroll
        for (int g = 0; g < G; ++g) ss[g] += __shfl_xor(ss[g], off);
    }
    if (lane == 0) {
        #pragma unroll
        for (int g = 0; g < G; ++g) psum[wave][g] = ss[g];
    }
    __syncthreads();

    #pragma unroll
    for (int g = 0; g < G; ++g) {
        float s = isItem ? (psum[2][g] + psum[3][g]) : (psum[0][g] + psum[1][g]);
        float denom = fmaxf(sqrtf(s), 1e-12f);
        float nv = val[g] / denom;
        const int b = b0 + g;
        out[(long)b * OUTROW + 2 + (isItem ? 128 : 0) + d] = nv;
        if (isItem) idst[((long)b * NI + ids[g][1]) * EDIM + d] = nv;
        else        udst[((long)b * NU + ids[g][0]) * EDIM + d] = nv;
    }
    if (t < 2 * G) {
        int g = t >> 1, col = t & 1;
        out[(long)(b0 + g) * OUTROW + col] = (float)ids[g][col];
    }
}

extern "C" void kernel_launch(void* const* d_in, const int* in_sizes, int n_in,
                              void* d_out, int out_size, void* d_ws, size_t ws_size,
                              hipStream_t stream) {
    const float* inputs = (const float*)d_in[0];
    const float* umem   = (const float*)d_in[1];
    const float* imem   = (const float*)d_in[2];
    const float* w_u    = (const float*)d_in[3];
    const float* bih_u  = (const float*)d_in[4];
    const float* bhh_u  = (const float*)d_in[5];
    const float* w_i    = (const float*)d_in[6];
    const float* bih_i  = (const float*)d_in[7];
    const float* bhh_i  = (const float*)d_in[8];
    float* out = (float*)d_out;

    const long OUTSEC = (long)BATCH * OUTROW;       // 264192
    const long MEMSZ  = (long)BATCH * NU * EDIM;    // 131072000
    float* udst = out + OUTSEC;
    float* idst = out + OUTSEC + MEMSZ;

    // 1) Big streaming copy first — no dependency on compute.
    dim3 cgrid(5120, 2);
    limnet_stream_copy<<<cgrid, 256, 0, stream>>>(
        (const f32x4*)umem, (const f32x4*)imem, (f32x4*)udst, (f32x4*)idst);

    // 2) Compute GRU + normalize; writes out section and scatters id-rows
    //    into the already-copied dst sections.
    limnet_compute<<<BATCH / G, 256, 0, stream>>>(
        inputs, umem, imem, w_u, bih_u, bhh_u, w_i, bih_i, bhh_i,
        out, udst, idst);
}